// Round 1
// baseline (269.274 us; speedup 1.0000x reference)
//
#include <hip/hip_runtime.h>
#include <hip/hip_cooperative_groups.h>
#include <math.h>

namespace cg = cooperative_groups;

#define DELTA_V 0.5f
#define DELTA_D 3.0f
#define P_REG   0.001f
#define TPB     256
#define NVMAX   36

typedef float f32x4 __attribute__((ext_vector_type(4)));
typedef int   i32x4 __attribute__((ext_vector_type(4)));

// ===================== fused cooperative kernel =====================
// Block balance: binary slice streams 3 x16B/elem-quad, instance 6 x16B.
// BPSB=64 (8 iters/thread, 384B) vs BPSI=128 (4 iters/thread, 384B) -> equal.
#define BPSB 64
#define BPSI 128
#define NBLK (4 * BPSB + 4 * BPSI)   // 768 blocks = 3 blocks/CU on 256 CUs

// fused-kernel ws layout (floats); every word read is written first.
#define FP1_OFF   0                       // [NBLK][36] pass1 partials
#define FCNT_OFF  (NBLK * NVMAX)          // [8][6]
#define FMEAN_OFF (FCNT_OFF + 48)         // [8][30]
#define FLDR_OFF  (FMEAN_OFF + 240)       // [8]
#define FP2_OFF   (FLDR_OFF + 8)          // [NBLK][6] pass2 partials

__device__ __forceinline__ int slice_block_base(int s) {
    return (s < 4) ? s * BPSB : 4 * BPSB + (s - 4) * BPSI;
}

// Redundant per-block reduction of this slice's pass-1 partials -> cnt, means (LDS).
template<int K, int D, int NBP>
__device__ void reduce_means(const float* __restrict__ ws, int sliceBase,
                             float* cntS, float* muS) {
    constexpr int NV = K * (D + 1);
    constexpr int G  = TPB / NV;          // 42 for (2,2), 7 for (6,5)
    __shared__ float red[TPB];
    __shared__ float tot[NVMAX];
    const int t = threadIdx.x;
    if (t < G * NV) {
        const int g = t / NV, v = t - g * NV;
        float sm = 0.f;
        for (int j = g; j < NBP; j += G)
            sm += ws[FP1_OFF + (size_t)(sliceBase + j) * NVMAX + v];
        red[t] = sm;
    }
    __syncthreads();
    if (t < NV) {
        float sm = 0.f;
        #pragma unroll
        for (int g = 0; g < G; ++g) sm += red[g * NV + t];
        tot[t] = sm;
        const int k = t / (D + 1), jj = t - k * (D + 1);
        if (jj == D) cntS[k] = sm;
    }
    __syncthreads();
    if (t < NV) {
        const int k = t / (D + 1), jj = t - k * (D + 1);
        if (jj < D) muS[k * D + jj] = tot[t] / cntS[k];
    }
    __syncthreads();
}

__device__ void final_body(const float* __restrict__ ws, float* __restrict__ out) {
    __shared__ float contrib[48];
    const int t = threadIdx.x;
    if (t < 48) {
        const int s = t / 6, k = t - s * 6;
        const int Ks = (s < 4) ? 2 : 6;
        const int NB = (s < 4) ? BPSB : BPSI;
        const int base = slice_block_base(s);
        float c = 0.f;
        if (k < Ks) {
            float v = 0.f;
            for (int j = 0; j < NB; ++j)
                v += ws[FP2_OFF + (size_t)(base + j) * 6 + k];
            c = v / ws[FCNT_OFF + s * 6 + k];
        }
        contrib[t] = c;
    }
    __syncthreads();
    if (t == 0) {
        float totB = 0.f, totI = 0.f;
        for (int s = 0; s < 8; ++s) {
            const int Ks = (s < 4) ? 2 : 6;
            float lv = 0.f;
            for (int k = 0; k < Ks; ++k) lv += contrib[s * 6 + k];
            lv /= (float)Ks;
            const float loss = lv + ws[FLDR_OFF + s];
            if (s < 4) totB += loss; else totI += loss;
        }
        out[0] = totB * 0.25f;
        out[1] = totI * 0.25f;
    }
}

// One slice, one block: load input ONCE into VGPRs, use it for both phases.
// NOTE: assumes n4 <= NITER*NBP*TPB (exact fit at MN=524288); guard handles short tails.
template<int K, int D, int NITER, int NBP>
__device__ void run_slice(const float* __restrict__ pred, const int* __restrict__ labels,
                          float* __restrict__ ws, float* __restrict__ out,
                          const int s, const int bx, const int bid, const int n4) {
    constexpr int NV = K * (D + 1);
    const f32x4* __restrict__ pred4 = (const f32x4*)pred;
    const i32x4* __restrict__ lab4  = (const i32x4*)labels;

    __shared__ float lredW[4][NVMAX];
    __shared__ float cntS[6];
    __shared__ float muS[30];

    f32x4 xv[NITER][D];   // retained logits (registers)
    int   lp[NITER];      // retained labels, 4 x 8-bit packed per iter

    const int idx0 = bx * TPB + threadIdx.x;
    const f32x4 zero4 = {0.f, 0.f, 0.f, 0.f};

    // ---- load everything once (all loads issued before any accumulation) ----
    #pragma unroll
    for (int it = 0; it < NITER; ++it) {
        const int i = idx0 + it * (NBP * TPB);
        if (i < n4) {
            const i32x4 l4 = lab4[i];
            lp[it] = l4[0] | (l4[1] << 8) | (l4[2] << 16) | (l4[3] << 24);
            #pragma unroll
            for (int d = 0; d < D; ++d) xv[it][d] = pred4[(size_t)d * n4 + i];
        } else {
            lp[it] = -1;  // 0xFF per byte: matches no label k
            #pragma unroll
            for (int d = 0; d < D; ++d) xv[it][d] = zero4;
        }
    }

    // ---- phase 1: per-label counts and sums ----
    float acc[K][D + 1];
    #pragma unroll
    for (int k = 0; k < K; ++k) {
        #pragma unroll
        for (int j = 0; j <= D; ++j) acc[k][j] = 0.f;
    }
    #pragma unroll
    for (int it = 0; it < NITER; ++it) {
        #pragma unroll
        for (int c = 0; c < 4; ++c) {
            const int lab = (lp[it] >> (8 * c)) & 0xFF;
            #pragma unroll
            for (int k = 0; k < K; ++k) {
                const float ind = (lab == k) ? 1.f : 0.f;
                acc[k][D] += ind;
                #pragma unroll
                for (int d = 0; d < D; ++d)
                    acc[k][d] = fmaf(ind, xv[it][d][c], acc[k][d]);
            }
        }
    }

    const int wave = threadIdx.x >> 6, lane = threadIdx.x & 63;
    #pragma unroll
    for (int k = 0; k < K; ++k) {
        #pragma unroll
        for (int j = 0; j <= D; ++j) {
            float v = acc[k][j];
            #pragma unroll
            for (int off = 32; off; off >>= 1) v += __shfl_down(v, off);
            if (lane == 0) lredW[wave][k * (D + 1) + j] = v;
        }
    }
    __syncthreads();
    if (threadIdx.x < NV)
        ws[FP1_OFF + (size_t)bid * NVMAX + threadIdx.x] =
            lredW[0][threadIdx.x] + lredW[1][threadIdx.x] +
            lredW[2][threadIdx.x] + lredW[3][threadIdx.x];

    cg::grid_group grid = cg::this_grid();
    grid.sync();

    // ---- phase 2a: every block redundantly reduces its own slice -> means ----
    reduce_means<K, D, NBP>(ws, bid - bx, cntS, muS);

    if (bx == 0) {   // one block per slice publishes cnt/means and computes dist+reg
        const int t = threadIdx.x;
        if (t < K) ws[FCNT_OFF + s * 6 + t] = cntS[t];
        if (t < K * D) ws[FMEAN_OFF + s * 30 + t] = muS[t];
        if (t == 0) {
            float l_dist = 0.f, l_reg = 0.f;
            for (int i = 0; i < K; ++i) {
                float n2 = 0.f;
                for (int d = 0; d < D; ++d) n2 += muS[i * D + d] * muS[i * D + d];
                l_reg += sqrtf(n2);
                for (int j = 0; j < K; ++j) {
                    if (i == j) continue;
                    float sq = 0.f;
                    for (int d = 0; d < D; ++d) {
                        const float df = muS[i * D + d] - muS[j * D + d];
                        sq += df * df;
                    }
                    const float dn = fmaxf(2.f * DELTA_D - sqrtf(sq), 0.f);
                    l_dist += dn * dn;
                }
            }
            ws[FLDR_OFF + s] = l_dist / (float)(K * (K - 1)) + P_REG * (l_reg / (float)K);
        }
    }

    // ---- phase 2b: hinged variance purely from retained registers ----
    float acc2[K];
    #pragma unroll
    for (int k = 0; k < K; ++k) acc2[k] = 0.f;
    #pragma unroll
    for (int it = 0; it < NITER; ++it) {
        #pragma unroll
        for (int c = 0; c < 4; ++c) {
            const int lab = (lp[it] >> (8 * c)) & 0xFF;
            const int lb  = (lab < K) ? lab : 0;   // safe LDS index for pad lanes
            float sq = 0.f;
            #pragma unroll
            for (int d = 0; d < D; ++d) {
                const float df = muS[lb * D + d] - xv[it][d][c];
                sq = fmaf(df, df, sq);
            }
            const float h  = fmaxf(sqrtf(sq) - DELTA_V, 0.f);
            const float h2 = h * h;
            #pragma unroll
            for (int k = 0; k < K; ++k) acc2[k] += (lab == k) ? h2 : 0.f;
        }
    }
    #pragma unroll
    for (int k = 0; k < K; ++k) {
        float v = acc2[k];
        #pragma unroll
        for (int off = 32; off; off >>= 1) v += __shfl_down(v, off);
        if (lane == 0) lredW[wave][k] = v;
    }
    __syncthreads();
    if (threadIdx.x < K)
        ws[FP2_OFF + (size_t)bid * 6 + threadIdx.x] =
            lredW[0][threadIdx.x] + lredW[1][threadIdx.x] +
            lredW[2][threadIdx.x] + lredW[3][threadIdx.x];

    grid.sync();

    if (bid == 0) final_body(ws, out);
}

__global__ __launch_bounds__(TPB, 3)   // 3 waves/EU -> 3 blocks/CU -> 768 co-resident
void fused_kernel(const float* __restrict__ bl, const int* __restrict__ bL,
                  const float* __restrict__ il, const int* __restrict__ iL,
                  float* __restrict__ ws, float* __restrict__ out, int MN) {
    const int bid = blockIdx.x;
    const int n4  = MN >> 2;
    if (bid < 4 * BPSB) {
        const int s = bid / BPSB, bx = bid - s * BPSB;
        run_slice<2, 2, 8, BPSB>(bl + (size_t)s * 2 * MN, bL + (size_t)s * MN,
                                 ws, out, s, bx, bid, n4);
    } else {
        const int r = bid - 4 * BPSB;
        const int si = r / BPSI, bx = r - si * BPSI;
        run_slice<6, 5, 4, BPSI>(il + (size_t)si * 5 * MN, iL + (size_t)si * MN,
                                 ws, out, 4 + si, bx, bid, n4);
    }
}

// ===================== fallback: previous 4-kernel pipeline =====================
#define OBPS 128
#define P1_OFF   0
#define CNT_OFF  (8 * OBPS * 36)
#define MEAN_OFF (CNT_OFF + 48)
#define LDR_OFF  (MEAN_OFF + 240)
#define P2_OFF   (LDR_OFF + 8)

template<int K, int D>
__device__ void pass1_body(const float* __restrict__ pred,
                           const int*  __restrict__ labels,
                           float* __restrict__ partials,
                           int n4, float (*lredW)[NVMAX]) {
    constexpr int NV = K * (D + 1);
    const float4* pred4 = (const float4*)pred;
    const int4*   lab4  = (const int4*)labels;

    float acc[K][D + 1];
    #pragma unroll
    for (int k = 0; k < K; ++k) {
        #pragma unroll
        for (int j = 0; j <= D; ++j) acc[k][j] = 0.f;
    }

    const int idx0   = blockIdx.x * TPB + threadIdx.x;
    const int stride = OBPS * TPB;
    for (int i = idx0; i < n4; i += stride) {
        int4 lv = lab4[i];
        int labs[4] = {lv.x, lv.y, lv.z, lv.w};
        float4 xvv[D];
        #pragma unroll
        for (int d = 0; d < D; ++d) xvv[d] = pred4[(size_t)d * n4 + i];
        const float* xs = (const float*)&xvv[0];
        #pragma unroll
        for (int c = 0; c < 4; ++c) {
            const int lab = labs[c];
            #pragma unroll
            for (int k = 0; k < K; ++k) {
                const float ind = (lab == k) ? 1.f : 0.f;
                acc[k][D] += ind;
                #pragma unroll
                for (int d = 0; d < D; ++d)
                    acc[k][d] = fmaf(ind, xs[d * 4 + c], acc[k][d]);
            }
        }
    }

    const int wave = threadIdx.x >> 6, lane = threadIdx.x & 63;
    #pragma unroll
    for (int k = 0; k < K; ++k) {
        #pragma unroll
        for (int j = 0; j <= D; ++j) {
            float v = acc[k][j];
            for (int off = 32; off > 0; off >>= 1) v += __shfl_down(v, off);
            if (lane == 0) lredW[wave][k * (D + 1) + j] = v;
        }
    }
    __syncthreads();
    if (threadIdx.x < NV) {
        const int t = threadIdx.x;
        partials[t] = lredW[0][t] + lredW[1][t] + lredW[2][t] + lredW[3][t];
    }
}

__global__ __launch_bounds__(TPB)
void pass1_fused(const float* __restrict__ bl, const int* __restrict__ bL,
                 const float* __restrict__ il, const int* __restrict__ iL,
                 float* __restrict__ ws, int MN) {
    const int s = blockIdx.y, b = s & 3;
    __shared__ float lredW[4][NVMAX];
    float* partials = ws + P1_OFF + (size_t)(s * OBPS + blockIdx.x) * NVMAX;
    if (s < 4) pass1_body<2, 2>(bl + (size_t)b * 2 * MN, bL + (size_t)b * MN, partials, MN >> 2, lredW);
    else       pass1_body<6, 5>(il + (size_t)b * 5 * MN, iL + (size_t)b * MN, partials, MN >> 2, lredW);
}

__global__ void mid_kernel(float* __restrict__ ws) {
    const int s = blockIdx.x;
    const int isInst = s >> 2;
    const int K = isInst ? 6 : 2, D = isInst ? 5 : 2;
    const int NV = K * (D + 1);
    const float* P = ws + P1_OFF + (size_t)s * OBPS * NVMAX;
    const int t = threadIdx.x;
    __shared__ float tot[NVMAX];
    __shared__ float muS[30];
    __shared__ float cntS[6];
    if (t < NV) {
        float v = 0.f;
        for (int j = 0; j < OBPS; ++j) v += P[j * NVMAX + t];
        tot[t] = v;
        const int k = t / (D + 1), jj = t % (D + 1);
        if (jj == D) { cntS[k] = v; ws[CNT_OFF + s * 6 + k] = v; }
    }
    __syncthreads();
    if (t < NV) {
        const int k = t / (D + 1), jj = t % (D + 1);
        if (jj < D) {
            const float m = tot[t] / cntS[k];
            muS[k * D + jj] = m;
            ws[MEAN_OFF + s * 30 + k * D + jj] = m;
        }
    }
    __syncthreads();
    if (t == 0) {
        float l_dist = 0.f, l_reg = 0.f;
        for (int i = 0; i < K; ++i) {
            float n2 = 0.f;
            for (int d = 0; d < D; ++d) n2 += muS[i * D + d] * muS[i * D + d];
            l_reg += sqrtf(n2);
            for (int j = 0; j < K; ++j) {
                if (i == j) continue;
                float sq = 0.f;
                for (int d = 0; d < D; ++d) { const float df = muS[i * D + d] - muS[j * D + d]; sq += df * df; }
                const float dn = fmaxf(2.f * DELTA_D - sqrtf(sq), 0.f);
                l_dist += dn * dn;
            }
        }
        l_dist /= (float)(K * (K - 1));
        l_reg  /= (float)K;
        ws[LDR_OFF + s] = l_dist + P_REG * l_reg;
    }
}

template<int K, int D>
__device__ void pass2_body(const float* __restrict__ pred,
                           const int*  __restrict__ labels,
                           const float* __restrict__ means,
                           float* __restrict__ partials,
                           int n4, float* mu, float (*lredW)[6]) {
    if (threadIdx.x < K * D) mu[threadIdx.x] = means[threadIdx.x];
    __syncthreads();

    const float4* pred4 = (const float4*)pred;
    const int4*   lab4  = (const int4*)labels;

    float acc[K];
    #pragma unroll
    for (int k = 0; k < K; ++k) acc[k] = 0.f;

    const int idx0   = blockIdx.x * TPB + threadIdx.x;
    const int stride = OBPS * TPB;
    for (int i = idx0; i < n4; i += stride) {
        int4 lv = lab4[i];
        int labs[4] = {lv.x, lv.y, lv.z, lv.w};
        float4 xvv[D];
        #pragma unroll
        for (int d = 0; d < D; ++d) xvv[d] = pred4[(size_t)d * n4 + i];
        const float* xs = (const float*)&xvv[0];
        #pragma unroll
        for (int c = 0; c < 4; ++c) {
            const int lab = labs[c];
            float sq = 0.f;
            #pragma unroll
            for (int d = 0; d < D; ++d) {
                const float df = mu[lab * D + d] - xs[d * 4 + c];
                sq = fmaf(df, df, sq);
            }
            const float h = fmaxf(sqrtf(sq) - DELTA_V, 0.f);
            const float h2 = h * h;
            #pragma unroll
            for (int k = 0; k < K; ++k)
                acc[k] += (lab == k) ? h2 : 0.f;
        }
    }

    const int wave = threadIdx.x >> 6, lane = threadIdx.x & 63;
    #pragma unroll
    for (int k = 0; k < K; ++k) {
        float v = acc[k];
        for (int off = 32; off > 0; off >>= 1) v += __shfl_down(v, off);
        if (lane == 0) lredW[wave][k] = v;
    }
    __syncthreads();
    if (threadIdx.x < K) {
        const int t = threadIdx.x;
        partials[t] = lredW[0][t] + lredW[1][t] + lredW[2][t] + lredW[3][t];
    }
}

__global__ __launch_bounds__(TPB)
void pass2_fused(const float* __restrict__ bl, const int* __restrict__ bL,
                 const float* __restrict__ il, const int* __restrict__ iL,
                 float* __restrict__ ws, int MN) {
    const int s = blockIdx.y, b = s & 3;
    __shared__ float mu[30];
    __shared__ float lredW[4][6];
    const float* means = ws + MEAN_OFF + s * 30;
    float* partials = ws + P2_OFF + (size_t)(s * OBPS + blockIdx.x) * 6;
    if (s < 4) pass2_body<2, 2>(bl + (size_t)b * 2 * MN, bL + (size_t)b * MN, means, partials, MN >> 2, mu, lredW);
    else       pass2_body<6, 5>(il + (size_t)b * 5 * MN, iL + (size_t)b * MN, means, partials, MN >> 2, mu, lredW);
}

__global__ void final_kernel(const float* __restrict__ ws, float* __restrict__ out) {
    __shared__ float contrib[48];
    const int t = threadIdx.x;
    if (t < 48) {
        const int s = t / 6, k = t % 6;
        const int Ks = (s < 4) ? 2 : 6;
        float c = 0.f;
        if (k < Ks) {
            float v = 0.f;
            for (int j = 0; j < OBPS; ++j) v += ws[P2_OFF + (size_t)(s * OBPS + j) * 6 + k];
            c = v / ws[CNT_OFF + s * 6 + k];
        }
        contrib[t] = c;
    }
    __syncthreads();
    if (t == 0) {
        float totB = 0.f, totI = 0.f;
        for (int s = 0; s < 8; ++s) {
            const int Ks = (s < 4) ? 2 : 6;
            float lv = 0.f;
            for (int k = 0; k < Ks; ++k) lv += contrib[s * 6 + k];
            lv /= (float)Ks;
            const float loss = lv + ws[LDR_OFF + s];
            if (s < 4) totB += loss; else totI += loss;
        }
        out[0] = totB * 0.25f;
        out[1] = totI * 0.25f;
    }
}

// ===================== launch =====================
extern "C" void kernel_launch(void* const* d_in, const int* in_sizes, int n_in,
                              void* d_out, int out_size, void* d_ws, size_t ws_size,
                              hipStream_t stream) {
    const float* bl = (const float*)d_in[0];
    const int*   bL = (const int*)d_in[1];
    const float* il = (const float*)d_in[2];
    const int*   iL = (const int*)d_in[3];
    float* ws  = (float*)d_ws;
    float* out = (float*)d_out;

    const int B  = 4;
    int MN = in_sizes[1] / B;   // 524288

    void* args[] = {(void*)&bl, (void*)&bL, (void*)&il, (void*)&iL,
                    (void*)&ws, (void*)&out, (void*)&MN};
    hipError_t err = hipLaunchCooperativeKernel(
        reinterpret_cast<const void*>(&fused_kernel),
        dim3(NBLK), dim3(TPB), args, 0u, stream);

    if (err != hipSuccess) {
        // diagnostic fallback: previous verified 4-kernel pipeline (~141 us)
        (void)hipGetLastError();
        dim3 grid(OBPS, 8), block(TPB);
        pass1_fused<<<grid, block, 0, stream>>>(bl, bL, il, iL, ws, MN);
        mid_kernel<<<8, 64, 0, stream>>>(ws);
        pass2_fused<<<grid, block, 0, stream>>>(bl, bL, il, iL, ws, MN);
        final_kernel<<<1, 64, 0, stream>>>(ws, out);
    }
}

// Round 2
// 225.017 us; speedup vs baseline: 1.1967x; 1.1967x over previous
//
#include <hip/hip_runtime.h>
#include <math.h>

#define DELTA_V 0.5f
#define DELTA_D 3.0f
#define P_REG   0.001f
#define TPB     256
#define NVMAX   36

// Block-balanced grid: binary slices stream 48 B/elem-quad, instance 96 B.
// BPSB=128 (4 iters/thread) vs BPSI=256 (2 iters/thread) -> 192 B/thread both.
#define BPSB 128
#define BPSI 256
#define NBLK (4 * BPSB + 4 * BPSI)   // 1536 blocks

// float-offset layout in ws (every word read is written first; counter is
// zeroed by kernel A block 0 each launch, so workspace poison is harmless)
#define CTR_OFF   0                         // int counter at word 0
#define P1_OFF    16                        // [NBLK][NVMAX] pass1 partials
#define SCAL_OFF  (P1_OFF + NBLK * NVMAX)   // [8][8]: cnt[0..5], ldr at +6
#define P2_OFF    (SCAL_OFF + 64)           // [NBLK][6] pass2 partials

__device__ __forceinline__ int slice_base(int s) {
    return (s < 4) ? s * BPSB : 4 * BPSB + (s - 4) * BPSI;
}

// ---------------- Pass 1 body: per-label counts and sums (identical math to verified r0) ----------------
template<int K, int D>
__device__ void pass1_body(const float* __restrict__ pred,   // [D][MN] this slice
                           const int*  __restrict__ labels,  // [MN]
                           float* __restrict__ partials,     // [NVMAX] this block's slot
                           int n4, int bx, int stride,
                           float (*lredW)[NVMAX]) {
    constexpr int NV = K * (D + 1);
    const float4* pred4 = (const float4*)pred;
    const int4*   lab4  = (const int4*)labels;

    float acc[K][D + 1];
    #pragma unroll
    for (int k = 0; k < K; ++k)
        #pragma unroll
        for (int j = 0; j <= D; ++j) acc[k][j] = 0.f;

    const int idx0 = bx * TPB + threadIdx.x;
    for (int i = idx0; i < n4; i += stride) {
        int4 lv = lab4[i];
        int labs[4] = {lv.x, lv.y, lv.z, lv.w};
        float4 xv[D];
        #pragma unroll
        for (int d = 0; d < D; ++d) xv[d] = pred4[(size_t)d * n4 + i];
        const float* xs = (const float*)&xv[0];   // xs[d*4 + c]
        #pragma unroll
        for (int c = 0; c < 4; ++c) {
            const int lab = labs[c];
            #pragma unroll
            for (int k = 0; k < K; ++k) {
                const float ind = (lab == k) ? 1.f : 0.f;
                acc[k][D] += ind;
                #pragma unroll
                for (int d = 0; d < D; ++d)
                    acc[k][d] = fmaf(ind, xs[d * 4 + c], acc[k][d]);
            }
        }
    }

    const int wave = threadIdx.x >> 6, lane = threadIdx.x & 63;
    #pragma unroll
    for (int k = 0; k < K; ++k) {
        #pragma unroll
        for (int j = 0; j <= D; ++j) {
            float v = acc[k][j];
            for (int off = 32; off > 0; off >>= 1) v += __shfl_down(v, off);
            if (lane == 0) lredW[wave][k * (D + 1) + j] = v;
        }
    }
    __syncthreads();
    if (threadIdx.x < NV) {
        const int t = threadIdx.x;
        partials[t] = lredW[0][t] + lredW[1][t] + lredW[2][t] + lredW[3][t];
    }
}

__global__ __launch_bounds__(TPB)
void pass1_k(const float* __restrict__ bl, const int* __restrict__ bL,
             const float* __restrict__ il, const int* __restrict__ iL,
             float* __restrict__ ws, int MN) {
    // zero kernel B's completion counter (visible to B via kernel-boundary release)
    if (blockIdx.x == 0 && threadIdx.x == 0) ((int*)ws)[CTR_OFF] = 0;

    __shared__ float lredW[4][NVMAX];
    const int bid = blockIdx.x, n4 = MN >> 2;
    float* partials = ws + P1_OFF + (size_t)bid * NVMAX;
    if (bid < 4 * BPSB) {
        const int s = bid / BPSB, bx = bid - s * BPSB;
        pass1_body<2, 2>(bl + (size_t)s * 2 * MN, bL + (size_t)s * MN,
                         partials, n4, bx, BPSB * TPB, lredW);
    } else {
        const int r = bid - 4 * BPSB;
        const int si = r / BPSI, bx = r - si * BPSI;
        pass1_body<6, 5>(il + (size_t)si * 5 * MN, iL + (size_t)si * MN,
                         partials, n4, bx, BPSI * TPB, lredW);
    }
}

// ---------------- final fold (runs inside the LAST block of kernel B) ----------------
__device__ void final_body(const float* __restrict__ ws, float* __restrict__ out) {
    __shared__ float contrib[48];
    const int t = threadIdx.x;
    if (t < 48) {
        const int s = t / 6, k = t - (t / 6) * 6;
        const int Ks = (s < 4) ? 2 : 6;
        const int NB = (s < 4) ? BPSB : BPSI;
        const int base = slice_base(s);
        float c = 0.f;
        if (k < Ks) {
            float v = 0.f;
            for (int j = 0; j < NB; ++j)
                v += ws[P2_OFF + (size_t)(base + j) * 6 + k];
            c = v / ws[SCAL_OFF + s * 8 + k];
        }
        contrib[t] = c;
    }
    __syncthreads();
    if (t == 0) {
        float totB = 0.f, totI = 0.f;
        for (int s = 0; s < 8; ++s) {
            const int Ks = (s < 4) ? 2 : 6;
            float lv = 0.f;
            for (int k = 0; k < Ks; ++k) lv += contrib[s * 6 + k];
            lv /= (float)Ks;
            const float loss = lv + ws[SCAL_OFF + s * 8 + 6];
            if (s < 4) totB += loss; else totI += loss;
        }
        out[0] = totB * 0.25f;
        out[1] = totI * 0.25f;
    }
}

// ---------------- Pass 2: redundant means-reduce, hinged variance, last-block final ----------------
template<int K, int D, int NBP>
__device__ void pass2_slice(const float* __restrict__ pred,
                            const int*  __restrict__ labels,
                            float* __restrict__ ws, float* __restrict__ out,
                            const int s, const int bx, const int bid, const int n4) {
    constexpr int NV = K * (D + 1);
    __shared__ float tot[NVMAX];
    __shared__ float muS[30];
    __shared__ float cntS[6];
    __shared__ float lredW[4][6];
    __shared__ int lastFlag;
    const int t = threadIdx.x;
    const int sliceBase = bid - bx;

    // redundant per-block reduction of this slice's pass-1 partials (L2-resident, ~KBs)
    // serial over j: same summation order as the verified r0 mid_kernel
    if (t < NV) {
        const float* P = ws + P1_OFF + (size_t)sliceBase * NVMAX + t;
        float v = 0.f;
        for (int j = 0; j < NBP; ++j) v += P[(size_t)j * NVMAX];
        tot[t] = v;
        const int k = t / (D + 1), jj = t - k * (D + 1);
        if (jj == D) cntS[k] = v;
    }
    __syncthreads();
    if (t < NV) {
        const int k = t / (D + 1), jj = t - k * (D + 1);
        if (jj < D) muS[k * D + jj] = tot[t] / cntS[k];
    }
    __syncthreads();

    // block 0 of each slice publishes cnt + (dist + reg) scalar for the final fold
    if (bx == 0) {
        if (t < K) ws[SCAL_OFF + s * 8 + t] = cntS[t];
        if (t == 0) {
            float l_dist = 0.f, l_reg = 0.f;
            for (int i = 0; i < K; ++i) {
                float n2 = 0.f;
                for (int d = 0; d < D; ++d) n2 += muS[i * D + d] * muS[i * D + d];
                l_reg += sqrtf(n2);
                for (int j = 0; j < K; ++j) {
                    if (i == j) continue;
                    float sq = 0.f;
                    for (int d = 0; d < D; ++d) {
                        const float df = muS[i * D + d] - muS[j * D + d];
                        sq += df * df;
                    }
                    const float dn = fmaxf(2.f * DELTA_D - sqrtf(sq), 0.f);
                    l_dist += dn * dn;
                }
            }
            ws[SCAL_OFF + s * 8 + 6] =
                l_dist / (float)(K * (K - 1)) + P_REG * (l_reg / (float)K);
        }
    }

    // streaming hinged-variance pass (identical math to verified r0 pass2_body)
    const float4* pred4 = (const float4*)pred;
    const int4*   lab4  = (const int4*)labels;

    float acc[K];
    #pragma unroll
    for (int k = 0; k < K; ++k) acc[k] = 0.f;

    const int idx0 = bx * TPB + t;
    const int stride = NBP * TPB;
    for (int i = idx0; i < n4; i += stride) {
        int4 lv = lab4[i];
        int labs[4] = {lv.x, lv.y, lv.z, lv.w};
        float4 xv[D];
        #pragma unroll
        for (int d = 0; d < D; ++d) xv[d] = pred4[(size_t)d * n4 + i];
        const float* xs = (const float*)&xv[0];
        #pragma unroll
        for (int c = 0; c < 4; ++c) {
            const int lab = labs[c];
            float sq = 0.f;
            #pragma unroll
            for (int d = 0; d < D; ++d) {
                const float df = muS[lab * D + d] - xs[d * 4 + c];
                sq = fmaf(df, df, sq);
            }
            const float h = fmaxf(sqrtf(sq) - DELTA_V, 0.f);
            const float h2 = h * h;
            #pragma unroll
            for (int k = 0; k < K; ++k)
                acc[k] += (lab == k) ? h2 : 0.f;
        }
    }

    const int wave = t >> 6, lane = t & 63;
    #pragma unroll
    for (int k = 0; k < K; ++k) {
        float v = acc[k];
        for (int off = 32; off > 0; off >>= 1) v += __shfl_down(v, off);
        if (lane == 0) lredW[wave][k] = v;
    }
    __syncthreads();
    if (t < K)
        ws[P2_OFF + (size_t)bid * 6 + t] =
            lredW[0][t] + lredW[1][t] + lredW[2][t] + lredW[3][t];

    // last-block-done: release this block's writes, count completions
    __syncthreads();
    if (t == 0) {
        __threadfence();   // agent-scope release: flush this XCD's L2
        const int old = __hip_atomic_fetch_add((int*)ws + CTR_OFF, 1,
                                               __ATOMIC_ACQ_REL,
                                               __HIP_MEMORY_SCOPE_AGENT);
        lastFlag = (old == NBLK - 1);
    }
    __syncthreads();
    if (lastFlag) {
        __threadfence();   // agent-scope acquire: invalidate stale cache lines
        final_body(ws, out);
    }
}

__global__ __launch_bounds__(TPB)
void pass2_k(const float* __restrict__ bl, const int* __restrict__ bL,
             const float* __restrict__ il, const int* __restrict__ iL,
             float* __restrict__ ws, float* __restrict__ out, int MN) {
    const int bid = blockIdx.x, n4 = MN >> 2;
    if (bid < 4 * BPSB) {
        const int s = bid / BPSB, bx = bid - s * BPSB;
        pass2_slice<2, 2, BPSB>(bl + (size_t)s * 2 * MN, bL + (size_t)s * MN,
                                ws, out, s, bx, bid, n4);
    } else {
        const int r = bid - 4 * BPSB;
        const int si = r / BPSI, bx = r - si * BPSI;
        pass2_slice<6, 5, BPSI>(il + (size_t)si * 5 * MN, iL + (size_t)si * MN,
                                ws, out, 4 + si, bx, bid, n4);
    }
}

// ---------------- launch: two plain (graph-friendly) dispatches ----------------
extern "C" void kernel_launch(void* const* d_in, const int* in_sizes, int n_in,
                              void* d_out, int out_size, void* d_ws, size_t ws_size,
                              hipStream_t stream) {
    const float* bl = (const float*)d_in[0];
    const int*   bL = (const int*)d_in[1];
    const float* il = (const float*)d_in[2];
    const int*   iL = (const int*)d_in[3];
    float* ws  = (float*)d_ws;
    float* out = (float*)d_out;

    const int B  = 4;
    const int MN = in_sizes[1] / B;   // 524288

    pass1_k<<<dim3(NBLK), dim3(TPB), 0, stream>>>(bl, bL, il, iL, ws, MN);
    pass2_k<<<dim3(NBLK), dim3(TPB), 0, stream>>>(bl, bL, il, iL, ws, out, MN);
}

// Round 3
// 139.388 us; speedup vs baseline: 1.9318x; 1.6143x over previous
//
#include <hip/hip_runtime.h>
#include <math.h>

#define DELTA_V 0.5f
#define DELTA_D 3.0f
#define P_REG   0.001f
#define TPB     256
#define NVMAX   36

// Block-balanced grid: binary slices stream 48 B/elem-quad, instance 96 B.
// BPSB=64 (8 iters/thread) vs BPSI=128 (4 iters/thread) -> 384 B/thread both.
#define BPSB 64
#define BPSI 128
#define NBLK (4 * BPSB + 4 * BPSI)   // 768 blocks = 3 blocks/CU

// float-offset ws layout; every word read is written first (poison-safe).
// P1 is TRANSPOSED: [NVMAX][NBLK] so pass2's reduce reads contiguous rows.
#define P1_OFF    0
#define SCAL_OFF  (P1_OFF + NVMAX * NBLK)   // [8][8]: cnt[0..5], ldr at +6
#define P2_OFF    (SCAL_OFF + 64)           // [NBLK][6] pass2 partials

__device__ __forceinline__ int slice_base(int s) {
    return (s < 4) ? s * BPSB : 4 * BPSB + (s - 4) * BPSI;
}

// ---------------- Pass 1: per-label counts and sums (math identical to verified r0) ----------------
template<int K, int D>
__device__ void pass1_body(const float* __restrict__ pred,   // [D][MN] this slice
                           const int*  __restrict__ labels,  // [MN]
                           float* __restrict__ ws,
                           int n4, int bx, int stride, int bid,
                           float (*lredW)[NVMAX]) {
    constexpr int NV = K * (D + 1);
    const float4* pred4 = (const float4*)pred;
    const int4*   lab4  = (const int4*)labels;

    float acc[K][D + 1];
    #pragma unroll
    for (int k = 0; k < K; ++k)
        #pragma unroll
        for (int j = 0; j <= D; ++j) acc[k][j] = 0.f;

    int i = bx * TPB + threadIdx.x;
    bool valid = (i < n4);

    // register double-buffer: loads for iteration j+1 issue before processing j
    int4   lv;
    float4 xv[D];
    if (valid) {
        lv = lab4[i];
        #pragma unroll
        for (int d = 0; d < D; ++d) xv[d] = pred4[(size_t)d * n4 + i];
    }
    while (valid) {
        const int  inext = i + stride;
        const bool vnext = (inext < n4);
        int4   lvn;
        float4 xvn[D];
        if (vnext) {
            lvn = lab4[inext];
            #pragma unroll
            for (int d = 0; d < D; ++d) xvn[d] = pred4[(size_t)d * n4 + inext];
        }

        int labs[4] = {lv.x, lv.y, lv.z, lv.w};
        const float* xs = (const float*)&xv[0];   // xs[d*4 + c]
        #pragma unroll
        for (int c = 0; c < 4; ++c) {
            const int lab = labs[c];
            #pragma unroll
            for (int k = 0; k < K; ++k) {
                const float ind = (lab == k) ? 1.f : 0.f;
                acc[k][D] += ind;
                #pragma unroll
                for (int d = 0; d < D; ++d)
                    acc[k][d] = fmaf(ind, xs[d * 4 + c], acc[k][d]);
            }
        }

        i = inext; valid = vnext;
        lv = lvn;
        #pragma unroll
        for (int d = 0; d < D; ++d) xv[d] = xvn[d];
    }

    const int wave = threadIdx.x >> 6, lane = threadIdx.x & 63;
    #pragma unroll
    for (int k = 0; k < K; ++k) {
        #pragma unroll
        for (int j = 0; j <= D; ++j) {
            float v = acc[k][j];
            for (int off = 32; off > 0; off >>= 1) v += __shfl_down(v, off);
            if (lane == 0) lredW[wave][k * (D + 1) + j] = v;
        }
    }
    __syncthreads();
    if (threadIdx.x < NV) {
        const int t = threadIdx.x;
        // transposed partials write: row t, column bid
        ws[P1_OFF + (size_t)t * NBLK + bid] =
            lredW[0][t] + lredW[1][t] + lredW[2][t] + lredW[3][t];
    }
}

__global__ __launch_bounds__(TPB)
void pass1_k(const float* __restrict__ bl, const int* __restrict__ bL,
             const float* __restrict__ il, const int* __restrict__ iL,
             float* __restrict__ ws, int MN) {
    __shared__ float lredW[4][NVMAX];
    const int bid = blockIdx.x, n4 = MN >> 2;
    if (bid < 4 * BPSB) {
        const int s = bid / BPSB, bx = bid - s * BPSB;
        pass1_body<2, 2>(bl + (size_t)s * 2 * MN, bL + (size_t)s * MN,
                         ws, n4, bx, BPSB * TPB, bid, lredW);
    } else {
        const int r = bid - 4 * BPSB;
        const int si = r / BPSI, bx = r - si * BPSI;
        pass1_body<6, 5>(il + (size_t)si * 5 * MN, iL + (size_t)si * MN,
                         ws, n4, bx, BPSI * TPB, bid, lredW);
    }
}

// ---------------- Pass 2: redundant means-reduce + hinged variance ----------------
template<int K, int D, int NBP>
__device__ void pass2_slice(const float* __restrict__ pred,
                            const int*  __restrict__ labels,
                            float* __restrict__ ws,
                            const int s, const int bx, const int bid, const int n4) {
    constexpr int NV = K * (D + 1);
    __shared__ float tot[NVMAX];
    __shared__ float muS[30];
    __shared__ float cntS[6];
    __shared__ float lredW[4][6];
    const int t = threadIdx.x;
    const int sliceBase = bid - bx;

    // redundant per-block reduction over this slice's transposed partials:
    // thread t streams a CONTIGUOUS row of NBP floats (same j-ascending order
    // as the verified r0 mid_kernel -> identical FP result across blocks).
    if (t < NV) {
        const float* P = ws + P1_OFF + (size_t)t * NBLK + sliceBase;
        float v = 0.f;
        #pragma unroll 8
        for (int j = 0; j < NBP; ++j) v += P[j];
        tot[t] = v;
        const int k = t / (D + 1), jj = t - k * (D + 1);
        if (jj == D) cntS[k] = v;
    }
    __syncthreads();
    if (t < NV) {
        const int k = t / (D + 1), jj = t - k * (D + 1);
        if (jj < D) muS[k * D + jj] = tot[t] / cntS[k];
    }
    __syncthreads();

    // block 0 of each slice publishes cnt + (dist + reg) scalar
    if (bx == 0) {
        if (t < K) ws[SCAL_OFF + s * 8 + t] = cntS[t];
        if (t == 0) {
            float l_dist = 0.f, l_reg = 0.f;
            for (int i = 0; i < K; ++i) {
                float n2 = 0.f;
                for (int d = 0; d < D; ++d) n2 += muS[i * D + d] * muS[i * D + d];
                l_reg += sqrtf(n2);
                for (int j = 0; j < K; ++j) {
                    if (i == j) continue;
                    float sq = 0.f;
                    for (int d = 0; d < D; ++d) {
                        const float df = muS[i * D + d] - muS[j * D + d];
                        sq += df * df;
                    }
                    const float dn = fmaxf(2.f * DELTA_D - sqrtf(sq), 0.f);
                    l_dist += dn * dn;
                }
            }
            ws[SCAL_OFF + s * 8 + 6] =
                l_dist / (float)(K * (K - 1)) + P_REG * (l_reg / (float)K);
        }
    }

    // streaming hinged-variance (math identical to verified r0), double-buffered
    const float4* pred4 = (const float4*)pred;
    const int4*   lab4  = (const int4*)labels;

    float acc[K];
    #pragma unroll
    for (int k = 0; k < K; ++k) acc[k] = 0.f;

    const int stride = NBP * TPB;
    int i = bx * TPB + t;
    bool valid = (i < n4);
    int4   lv;
    float4 xv[D];
    if (valid) {
        lv = lab4[i];
        #pragma unroll
        for (int d = 0; d < D; ++d) xv[d] = pred4[(size_t)d * n4 + i];
    }
    while (valid) {
        const int  inext = i + stride;
        const bool vnext = (inext < n4);
        int4   lvn;
        float4 xvn[D];
        if (vnext) {
            lvn = lab4[inext];
            #pragma unroll
            for (int d = 0; d < D; ++d) xvn[d] = pred4[(size_t)d * n4 + inext];
        }

        int labs[4] = {lv.x, lv.y, lv.z, lv.w};
        const float* xs = (const float*)&xv[0];
        #pragma unroll
        for (int c = 0; c < 4; ++c) {
            const int lab = labs[c];
            float sq = 0.f;
            #pragma unroll
            for (int d = 0; d < D; ++d) {
                const float df = muS[lab * D + d] - xs[d * 4 + c];
                sq = fmaf(df, df, sq);
            }
            const float h = fmaxf(sqrtf(sq) - DELTA_V, 0.f);
            const float h2 = h * h;
            #pragma unroll
            for (int k = 0; k < K; ++k)
                acc[k] += (lab == k) ? h2 : 0.f;
        }

        i = inext; valid = vnext;
        lv = lvn;
        #pragma unroll
        for (int d = 0; d < D; ++d) xv[d] = xvn[d];
    }

    const int wave = t >> 6, lane = t & 63;
    #pragma unroll
    for (int k = 0; k < K; ++k) {
        float v = acc[k];
        for (int off = 32; off > 0; off >>= 1) v += __shfl_down(v, off);
        if (lane == 0) lredW[wave][k] = v;
    }
    __syncthreads();
    if (t < K)
        ws[P2_OFF + (size_t)bid * 6 + t] =
            lredW[0][t] + lredW[1][t] + lredW[2][t] + lredW[3][t];
}

__global__ __launch_bounds__(TPB)
void pass2_k(const float* __restrict__ bl, const int* __restrict__ bL,
             const float* __restrict__ il, const int* __restrict__ iL,
             float* __restrict__ ws, int MN) {
    const int bid = blockIdx.x, n4 = MN >> 2;
    if (bid < 4 * BPSB) {
        const int s = bid / BPSB, bx = bid - s * BPSB;
        pass2_slice<2, 2, BPSB>(bl + (size_t)s * 2 * MN, bL + (size_t)s * MN,
                                ws, s, bx, bid, n4);
    } else {
        const int r = bid - 4 * BPSB;
        const int si = r / BPSI, bx = r - si * BPSI;
        pass2_slice<6, 5, BPSI>(il + (size_t)si * 5 * MN, iL + (size_t)si * MN,
                                ws, 4 + si, bx, bid, n4);
    }
}

// ---------------- Final: fold into 2 scalars (1 tiny block; coherence via kernel boundary) ----------------
__global__ void final_k(const float* __restrict__ ws, float* __restrict__ out) {
    __shared__ float contrib[48];
    const int t = threadIdx.x;
    if (t < 48) {
        const int s = t / 6, k = t - (t / 6) * 6;
        const int Ks = (s < 4) ? 2 : 6;
        const int NB = (s < 4) ? BPSB : BPSI;
        const int base = slice_base(s);
        float c = 0.f;
        if (k < Ks) {
            float v = 0.f;
            for (int j = 0; j < NB; ++j)
                v += ws[P2_OFF + (size_t)(base + j) * 6 + k];
            c = v / ws[SCAL_OFF + s * 8 + k];
        }
        contrib[t] = c;
    }
    __syncthreads();
    if (t == 0) {
        float totB = 0.f, totI = 0.f;
        for (int s = 0; s < 8; ++s) {
            const int Ks = (s < 4) ? 2 : 6;
            float lv = 0.f;
            for (int k = 0; k < Ks; ++k) lv += contrib[s * 6 + k];
            lv /= (float)Ks;
            const float loss = lv + ws[SCAL_OFF + s * 8 + 6];
            if (s < 4) totB += loss; else totI += loss;
        }
        out[0] = totB * 0.25f;
        out[1] = totI * 0.25f;
    }
}

// ---------------- launch: three plain (graph-friendly) dispatches, zero fences/atomics ----------------
extern "C" void kernel_launch(void* const* d_in, const int* in_sizes, int n_in,
                              void* d_out, int out_size, void* d_ws, size_t ws_size,
                              hipStream_t stream) {
    const float* bl = (const float*)d_in[0];
    const int*   bL = (const int*)d_in[1];
    const float* il = (const float*)d_in[2];
    const int*   iL = (const int*)d_in[3];
    float* ws  = (float*)d_ws;
    float* out = (float*)d_out;

    const int B  = 4;
    const int MN = in_sizes[1] / B;   // 524288

    pass1_k<<<dim3(NBLK), dim3(TPB), 0, stream>>>(bl, bL, il, iL, ws, MN);
    pass2_k<<<dim3(NBLK), dim3(TPB), 0, stream>>>(bl, bL, il, iL, ws, MN);
    final_k<<<dim3(1), dim3(64), 0, stream>>>(ws, out);
}

// Round 4
// 135.665 us; speedup vs baseline: 1.9849x; 1.0274x over previous
//
#include <hip/hip_runtime.h>
#include <math.h>

#define DELTA_V 0.5f
#define DELTA_D 3.0f
#define P_REG   0.001f
#define TPB     256
#define NVMAX   36

// Balanced grid: binary 4 iters x 48 B = instance 2 iters x 96 B = 49 KB/block.
// Exact fit at n4 = 131072: 128*256*4 = 256*256*2 = 131072.
#define BPSB 128
#define BPSI 256
#define NBLK (4 * BPSB + 4 * BPSI)   // 1536 blocks = 6/CU, 24 waves/CU

// float-offset ws layout; every word read is written first (poison-safe).
#define P1_OFF    0                             // [NVMAX][NBLK] transposed pass1 partials
#define LBL_OFF   (P1_OFF + NVMAX * NBLK)       // packed uchar labels: 8 * MN bytes = 2*MN floats
#define SCAL_OFF  (LBL_OFF + 2 * 524288)        // [8][8]: cnt[0..5], ldr at +6
#define P2_OFF    (SCAL_OFF + 64)               // [6][NBLK] transposed pass2 partials

__device__ __forceinline__ int slice_base(int s) {
    return (s < 4) ? s * BPSB : 4 * BPSB + (s - 4) * BPSI;
}

// ---------------- Pass 1: per-label counts/sums + label re-pack (math identical to verified r0) ----------------
template<int K, int D>
__device__ void pass1_body(const float* __restrict__ pred,   // [D][MN] this slice
                           const int*  __restrict__ labels,  // [MN]
                           float* __restrict__ ws,
                           uchar4* __restrict__ lblPack,     // [n4] this slice's packed labels
                           int n4, int bx, int stride, int bid,
                           float (*lredW)[NVMAX]) {
    constexpr int NV = K * (D + 1);
    const float4* pred4 = (const float4*)pred;
    const int4*   lab4  = (const int4*)labels;

    float acc[K][D + 1];
    #pragma unroll
    for (int k = 0; k < K; ++k)
        #pragma unroll
        for (int j = 0; j <= D; ++j) acc[k][j] = 0.f;

    for (int i = bx * TPB + threadIdx.x; i < n4; i += stride) {
        int4 lv = lab4[i];
        int labs[4] = {lv.x, lv.y, lv.z, lv.w};
        lblPack[i] = make_uchar4((unsigned char)lv.x, (unsigned char)lv.y,
                                 (unsigned char)lv.z, (unsigned char)lv.w);
        float4 xv[D];
        #pragma unroll
        for (int d = 0; d < D; ++d) xv[d] = pred4[(size_t)d * n4 + i];
        const float* xs = (const float*)&xv[0];   // xs[d*4 + c]
        #pragma unroll
        for (int c = 0; c < 4; ++c) {
            const int lab = labs[c];
            #pragma unroll
            for (int k = 0; k < K; ++k) {
                const float ind = (lab == k) ? 1.f : 0.f;
                acc[k][D] += ind;
                #pragma unroll
                for (int d = 0; d < D; ++d)
                    acc[k][d] = fmaf(ind, xs[d * 4 + c], acc[k][d]);
            }
        }
    }

    const int wave = threadIdx.x >> 6, lane = threadIdx.x & 63;
    #pragma unroll
    for (int k = 0; k < K; ++k) {
        #pragma unroll
        for (int j = 0; j <= D; ++j) {
            float v = acc[k][j];
            for (int off = 32; off > 0; off >>= 1) v += __shfl_down(v, off);
            if (lane == 0) lredW[wave][k * (D + 1) + j] = v;
        }
    }
    __syncthreads();
    if (threadIdx.x < NV) {
        const int t = threadIdx.x;
        ws[P1_OFF + (size_t)t * NBLK + bid] =   // transposed: row t, column bid
            lredW[0][t] + lredW[1][t] + lredW[2][t] + lredW[3][t];
    }
}

__global__ __launch_bounds__(TPB)
void pass1_k(const float* __restrict__ bl, const int* __restrict__ bL,
             const float* __restrict__ il, const int* __restrict__ iL,
             float* __restrict__ ws, int MN) {
    __shared__ float lredW[4][NVMAX];
    const int bid = blockIdx.x, n4 = MN >> 2;
    uchar4* lblBase = (uchar4*)(ws + LBL_OFF);
    if (bid < 4 * BPSB) {
        const int s = bid / BPSB, bx = bid - s * BPSB;
        pass1_body<2, 2>(bl + (size_t)s * 2 * MN, bL + (size_t)s * MN,
                         ws, lblBase + (size_t)s * n4, n4, bx, BPSB * TPB, bid, lredW);
    } else {
        const int r = bid - 4 * BPSB;
        const int si = r / BPSI, bx = r - si * BPSI;
        pass1_body<6, 5>(il + (size_t)si * 5 * MN, iL + (size_t)si * MN,
                         ws, lblBase + (size_t)(4 + si) * n4, n4, bx, BPSI * TPB, bid, lredW);
    }
}

// ---------------- Pass 2: redundant means-reduce + hinged variance (packed labels) ----------------
template<int K, int D, int NBP>
__device__ void pass2_slice(const float* __restrict__ pred,
                            const uchar4* __restrict__ lblPack,
                            float* __restrict__ ws,
                            const int s, const int bx, const int bid, const int n4) {
    constexpr int NV = K * (D + 1);
    __shared__ float tot[NVMAX];
    __shared__ float muS[30];
    __shared__ float cntS[6];
    __shared__ float lredW[4][6];
    const int t = threadIdx.x;
    const int sliceBase = bid - bx;

    // redundant per-block reduce of this slice's transposed partials:
    // thread t streams a CONTIGUOUS row of NBP floats, j ascending ->
    // bitwise-identical means in every block of the slice.
    if (t < NV) {
        const float* P = ws + P1_OFF + (size_t)t * NBLK + sliceBase;
        float v = 0.f;
        #pragma unroll 8
        for (int j = 0; j < NBP; ++j) v += P[j];
        tot[t] = v;
        const int k = t / (D + 1), jj = t - k * (D + 1);
        if (jj == D) cntS[k] = v;
    }
    __syncthreads();
    if (t < NV) {
        const int k = t / (D + 1), jj = t - k * (D + 1);
        if (jj < D) muS[k * D + jj] = tot[t] / cntS[k];
    }
    __syncthreads();

    // block 0 of each slice publishes cnt + (dist + reg) scalar
    if (bx == 0) {
        if (t < K) ws[SCAL_OFF + s * 8 + t] = cntS[t];
        if (t == 0) {
            float l_dist = 0.f, l_reg = 0.f;
            for (int i = 0; i < K; ++i) {
                float n2 = 0.f;
                for (int d = 0; d < D; ++d) n2 += muS[i * D + d] * muS[i * D + d];
                l_reg += sqrtf(n2);
                for (int j = 0; j < K; ++j) {
                    if (i == j) continue;
                    float sq = 0.f;
                    for (int d = 0; d < D; ++d) {
                        const float df = muS[i * D + d] - muS[j * D + d];
                        sq += df * df;
                    }
                    const float dn = fmaxf(2.f * DELTA_D - sqrtf(sq), 0.f);
                    l_dist += dn * dn;
                }
            }
            ws[SCAL_OFF + s * 8 + 6] =
                l_dist / (float)(K * (K - 1)) + P_REG * (l_reg / (float)K);
        }
    }

    // streaming hinged-variance pass: packed 1-byte labels (4 B/quad vs 16 B)
    const float4* pred4 = (const float4*)pred;

    float acc[K];
    #pragma unroll
    for (int k = 0; k < K; ++k) acc[k] = 0.f;

    const int stride = NBP * TPB;
    for (int i = bx * TPB + t; i < n4; i += stride) {
        const uchar4 lq = lblPack[i];
        int labs[4] = {lq.x, lq.y, lq.z, lq.w};
        float4 xv[D];
        #pragma unroll
        for (int d = 0; d < D; ++d) xv[d] = pred4[(size_t)d * n4 + i];
        const float* xs = (const float*)&xv[0];
        #pragma unroll
        for (int c = 0; c < 4; ++c) {
            const int lab = labs[c];
            float sq = 0.f;
            #pragma unroll
            for (int d = 0; d < D; ++d) {
                const float df = muS[lab * D + d] - xs[d * 4 + c];
                sq = fmaf(df, df, sq);
            }
            const float h = fmaxf(sqrtf(sq) - DELTA_V, 0.f);
            const float h2 = h * h;
            #pragma unroll
            for (int k = 0; k < K; ++k)
                acc[k] += (lab == k) ? h2 : 0.f;
        }
    }

    const int wave = t >> 6, lane = t & 63;
    #pragma unroll
    for (int k = 0; k < K; ++k) {
        float v = acc[k];
        for (int off = 32; off > 0; off >>= 1) v += __shfl_down(v, off);
        if (lane == 0) lredW[wave][k] = v;
    }
    __syncthreads();
    if (t < K)
        ws[P2_OFF + (size_t)t * NBLK + bid] =   // transposed: row k, column bid
            lredW[0][t] + lredW[1][t] + lredW[2][t] + lredW[3][t];
}

__global__ __launch_bounds__(TPB)
void pass2_k(const float* __restrict__ bl, const float* __restrict__ il,
             float* __restrict__ ws, int MN) {
    const int bid = blockIdx.x, n4 = MN >> 2;
    const uchar4* lblBase = (const uchar4*)(ws + LBL_OFF);
    if (bid < 4 * BPSB) {
        const int s = bid / BPSB, bx = bid - s * BPSB;
        pass2_slice<2, 2, BPSB>(bl + (size_t)s * 2 * MN, lblBase + (size_t)s * n4,
                                ws, s, bx, bid, n4);
    } else {
        const int r = bid - 4 * BPSB;
        const int si = r / BPSI, bx = r - si * BPSI;
        pass2_slice<6, 5, BPSI>(il + (size_t)si * 5 * MN, lblBase + (size_t)(4 + si) * n4,
                                ws, 4 + si, bx, bid, n4);
    }
}

// ---------------- Final: fold into 2 scalars (contiguous row reads) ----------------
__global__ void final_k(const float* __restrict__ ws, float* __restrict__ out) {
    __shared__ float contrib[48];
    const int t = threadIdx.x;
    if (t < 48) {
        const int s = t / 6, k = t - (t / 6) * 6;
        const int Ks = (s < 4) ? 2 : 6;
        const int NB = (s < 4) ? BPSB : BPSI;
        const int base = slice_base(s);
        float c = 0.f;
        if (k < Ks) {
            const float* P = ws + P2_OFF + (size_t)k * NBLK + base;
            float v = 0.f;
            #pragma unroll 8
            for (int j = 0; j < NB; ++j) v += P[j];
            c = v / ws[SCAL_OFF + s * 8 + k];
        }
        contrib[t] = c;
    }
    __syncthreads();
    if (t == 0) {
        float totB = 0.f, totI = 0.f;
        for (int s = 0; s < 8; ++s) {
            const int Ks = (s < 4) ? 2 : 6;
            float lv = 0.f;
            for (int k = 0; k < Ks; ++k) lv += contrib[s * 6 + k];
            lv /= (float)Ks;
            const float loss = lv + ws[SCAL_OFF + s * 8 + 6];
            if (s < 4) totB += loss; else totI += loss;
        }
        out[0] = totB * 0.25f;
        out[1] = totI * 0.25f;
    }
}

// ---------------- launch: three plain (graph-friendly) dispatches ----------------
extern "C" void kernel_launch(void* const* d_in, const int* in_sizes, int n_in,
                              void* d_out, int out_size, void* d_ws, size_t ws_size,
                              hipStream_t stream) {
    const float* bl = (const float*)d_in[0];
    const int*   bL = (const int*)d_in[1];
    const float* il = (const float*)d_in[2];
    const int*   iL = (const int*)d_in[3];
    float* ws  = (float*)d_ws;
    float* out = (float*)d_out;

    const int B  = 4;
    const int MN = in_sizes[1] / B;   // 524288

    pass1_k<<<dim3(NBLK), dim3(TPB), 0, stream>>>(bl, bL, il, iL, ws, MN);
    pass2_k<<<dim3(NBLK), dim3(TPB), 0, stream>>>(bl, il, ws, MN);
    final_k<<<dim3(1), dim3(64), 0, stream>>>(ws, out);
}